// Round 1
// baseline (222.152 us; speedup 1.0000x reference)
//
#include <hip/hip_runtime.h>
#include <math.h>

#define DD   128      // hidden dim
#define LL   32       // sequence length
#define MS   32       // sequences per block
#define NT   1024     // 16 waves: 8 consumer + 8 producer
#define NSEQ 8192     // B*S
#define XP   136      // x/h LDS row pitch in ushorts (272 B, 16B-aligned)
#define GP   36       // gx row pitch in floats (144 B, 16B-aligned)
#define OLP  36       // outl pitch in floats

#define GX_ELEMS   (384 * GP)                       // floats per gx slot
#define SMEM_XH_X  (2 * 384 * GP * 4)               // 110592
#define SMEM_XH_H  (SMEM_XH_X + 2 * MS * XP * 2)    // +17408
#define SMEM_OUTL  (SMEM_XH_H + 2 * MS * XP * 2)    // +17408
#define SMEM_WOFL  (SMEM_OUTL + MS * OLP * 4)       // +4608
#define SMEM_TOTAL (SMEM_WOFL + 4 * 64 * 8 * 2)     // +4096 = 154112

typedef short bf16x8 __attribute__((ext_vector_type(8)));   // 8 bf16 = 4 VGPRs
typedef float f32x4  __attribute__((ext_vector_type(4)));

#define MFMA __builtin_amdgcn_mfma_f32_16x16x32_bf16

__device__ __forceinline__ unsigned short f2bf(float f) {
    unsigned u = __float_as_uint(f);
    u += 0x7fffu + ((u >> 16) & 1u);          // round-to-nearest-even
    return (unsigned short)(u >> 16);
}

#if __has_builtin(__builtin_amdgcn_cvt_pk_bf16_f32)
typedef __bf16 bf16x2_t __attribute__((ext_vector_type(2)));
__device__ __forceinline__ unsigned pack2(float a, float b) {
    union { bf16x2_t v; unsigned u; } c;
    c.v = __builtin_amdgcn_cvt_pk_bf16_f32(a, b);
    return c.u;
}
#else
__device__ __forceinline__ unsigned pack2(float a, float b) {
    return (unsigned)f2bf(a) | ((unsigned)f2bf(b) << 16);
}
#endif

__device__ __forceinline__ void pack8(float4 a, float4 b, unsigned short* dst) {
    union { unsigned u[4]; bf16x8 v; } pk;
    pk.u[0] = pack2(a.x, a.y); pk.u[1] = pack2(a.z, a.w);
    pk.u[2] = pack2(b.x, b.y); pk.u[3] = pack2(b.z, b.w);
    *(bf16x8*)dst = pk.v;
}

__device__ __forceinline__ float fast_rcp(float x) {
    return __builtin_amdgcn_rcpf(x);   // v_rcp_f32, ~1 ulp — fine at bf16 output
}

// ---------------------------------------------------------------------------
// Prep: swizzle W_ih / W_hh into per-gate MFMA B-fragments, bf16.
// Frag index F = ((side*3 + g)*8 + sl)*4 + kk   (side 0=W_ih, 1=W_hh;
// g 0=r,1=z,2=n; sl = 16-dim slice 0..7; kk = K-subtile 0..3).
// Element j of lane (n=lane&15, q=lane>>4):
//   W_side[(g*128 + sl*16 + n) * 128 + (kk*32 + q*8 + j)]
// ---------------------------------------------------------------------------
__global__ void prep_weights(const float* __restrict__ Wih,
                             const float* __restrict__ Whh,
                             unsigned short* __restrict__ Wfrag) {
    int idx  = blockIdx.x * blockDim.x + threadIdx.x;   // 0 .. 98303
    int j    = idx & 7;
    int lane = (idx >> 3) & 63;
    int kk   = (idx >> 9) & 3;
    int sl   = (idx >> 11) & 7;
    int sg   = idx >> 14;            // 0..5 = side*3 + g
    int n = lane & 15, q = lane >> 4;
    int k  = kk * 32 + q * 8 + j;
    int g  = (sg >= 3) ? sg - 3 : sg;
    int gd = g * 128 + sl * 16 + n;
    const float* src = (sg >= 3) ? Whh : Wih;
    Wfrag[idx] = f2bf(src[gd * 128 + k]);
}

// ---------------------------------------------------------------------------
// Wave-specialized GRU:
//   waves 0..7  (consumer): h-side GEMM (K=128) + gate math + h-write.
//   waves 8..15 (producer): x staging, x-side GEMM 1 step ahead into a
//                           depth-2 f32 gx ring in LDS, out-projection.
// Each role holds only its 12 weight fragments (48 VGPRs) -> whole kernel
// fits <=128 VGPR -> 16 waves resident (4/SIMD, 50% occupancy).
// One __syncthreads per step; both branch paths execute exactly 35 barriers.
// ---------------------------------------------------------------------------
__global__ __launch_bounds__(NT, 4) void gru_mfma(
    const float* __restrict__ x,      // [8192][32][128]
    const float* __restrict__ h0,     // [8192][128]
    const unsigned short* __restrict__ Wfrag,
    const float* __restrict__ b_ih,   // [384]
    const float* __restrict__ b_hh,   // [384]
    const float* __restrict__ w_out,  // [128]
    const float* __restrict__ b_out,  // [1]
    float* __restrict__ out)          // [8192][32]
{
    extern __shared__ char smem[];
    float*          gxs  = (float*)(smem);                       // [2][384][GP]
    unsigned short* xhx  = (unsigned short*)(smem + SMEM_XH_X);  // [2][MS][XP]
    unsigned short* xhh  = (unsigned short*)(smem + SMEM_XH_H);  // [2][MS][XP]
    float*          outl = (float*)(smem + SMEM_OUTL);           // [MS][OLP]
    unsigned short* wofl = (unsigned short*)(smem + SMEM_WOFL);  // [2048]

    const int tid  = threadIdx.x;
    const int n0   = blockIdx.x * MS;
    const int wv   = tid >> 6;       // 0..15
    const int lane = tid & 63;
    const int ln   = lane & 15;      // MFMA col (dim-in-slice)
    const int q    = lane >> 4;      // quad (rows q*4..q*4+3)
    const bf16x8* W = (const bf16x8*)Wfrag;

    if (wv < 8) {
        // ================= CONSUMER =================
        const int d = wv * 16 + ln;
        const float bhr = b_hh[d], bhz = b_hh[DD + d], bhn = b_hh[2*DD + d];

        bf16x8 whr[4], whz[4], whn[4];
        #pragma unroll
        for (int kk = 0; kk < 4; ++kk) {
            whr[kk] = W[((24 + wv)*4 + kk)*64 + lane];
            whz[kk] = W[((32 + wv)*4 + kk)*64 + lane];
            whn[kk] = W[((40 + wv)*4 + kk)*64 + lane];
        }

        // stage W_out B-fragment (col 0 = w_out, cols 1..15 = 0)
        #pragma unroll
        for (int e = 0; e < 4; ++e) {
            int idx = tid * 4 + e;              // 0..2047
            int j   = idx & 7;
            int l2  = (idx >> 3) & 63;
            int kk  = idx >> 9;                 // 0..3
            int n2 = l2 & 15, q2 = l2 >> 4;
            wofl[idx] = (n2 == 0) ? f2bf(w_out[kk * 32 + q2 * 8 + j])
                                  : (unsigned short)0;
        }
        // stage h0 (bf16) into xhh slot 0
        {
            const int gn = tid >> 4, gd8 = (tid & 15) * 8;
            const float* hb = h0 + (size_t)(n0 + gn) * DD + gd8;
            pack8(*(const float4*)hb, *(const float4*)(hb + 4),
                  &xhh[gn * XP + gd8]);
        }
        // fp32 hidden state in C-layout: rows tl*16+q*4+i, dim d
        float hprev[8];
        #pragma unroll
        for (int tl = 0; tl < 2; ++tl)
            #pragma unroll
            for (int i = 0; i < 4; ++i)
                hprev[tl*4+i] = h0[(size_t)(n0 + tl*16 + q*4 + i) * DD + d];

        __syncthreads();   // #1: staging done
        __syncthreads();   // #2: gx[0] ready

        for (int t = 0; t < LL; ++t) {
            const int sl_ = t & 1;
            const float* gr = gxs + sl_ * GX_ELEMS;
            f32x4 cr[2], cz[2], ch[2];
            #pragma unroll
            for (int tl = 0; tl < 2; ++tl) {
                const int co = tl*16 + q*4;
                cr[tl] = *(const f32x4*)&gr[(d)*GP + co];
                cz[tl] = *(const f32x4*)&gr[(DD + d)*GP + co];
                ch[tl] = (f32x4){0.f, 0.f, 0.f, 0.f};
            }
            const unsigned short* hr0 = &xhh[sl_*MS*XP + ln*XP];
            const unsigned short* hr1 = hr0 + 16*XP;
            #pragma unroll
            for (int kk = 0; kk < 4; ++kk) {
                bf16x8 a0 = *(const bf16x8*)(hr0 + kk*32 + q*8);
                bf16x8 a1 = *(const bf16x8*)(hr1 + kk*32 + q*8);
                cr[0] = MFMA(a0, whr[kk], cr[0], 0,0,0);
                cr[1] = MFMA(a1, whr[kk], cr[1], 0,0,0);
                cz[0] = MFMA(a0, whz[kk], cz[0], 0,0,0);
                cz[1] = MFMA(a1, whz[kk], cz[1], 0,0,0);
                ch[0] = MFMA(a0, whn[kk], ch[0], 0,0,0);
                ch[1] = MFMA(a1, whn[kk], ch[1], 0,0,0);
            }
            // n-gate x-side preacts read late (short live range)
            f32x4 gnx[2];
            #pragma unroll
            for (int tl = 0; tl < 2; ++tl)
                gnx[tl] = *(const f32x4*)&gr[(2*DD + d)*GP + tl*16 + q*4];

            unsigned short* hw = xhh + (sl_ ^ 1)*MS*XP;
            #pragma unroll
            for (int tl = 0; tl < 2; ++tl)
                #pragma unroll
                for (int i = 0; i < 4; ++i) {
                    const float rr = fast_rcp(1.f + __expf(-(cr[tl][i] + bhr)));
                    const float zz = fast_rcp(1.f + __expf(-(cz[tl][i] + bhz)));
                    const float aa = gnx[tl][i] + rr * (ch[tl][i] + bhn);
                    // tanh(aa) = 2/(1+exp(-2a)) - 1 : NaN-free, no clamp needed
                    const float ee = __expf(-2.f * aa);
                    const float th = 2.f * fast_rcp(1.f + ee) - 1.f;
                    const float hh = th + zz * (hprev[tl*4+i] - th);
                    hprev[tl*4+i] = hh;
                    hw[(tl*16 + q*4 + i)*XP + d] = f2bf(hh);
                }
            __syncthreads();   // #3..#34
        }
        __syncthreads();       // #35: outl col 31 ready

        // coalesced flush: block's 32x32 outputs are contiguous in global
        if (tid < 256) {
            const int row = tid >> 3;
            const int t4  = (tid & 7) * 4;
            float4 v = *(const float4*)&outl[row * OLP + t4];
            *(float4*)(out + (size_t)(n0 + row) * LL + t4) = v;
        }
    } else {
        // ================= PRODUCER =================
        const int pv = wv - 8;
        const int dp = pv * 16 + ln;
        const float bir  = b_ih[dp];
        const float biz  = b_ih[DD + dp];
        const float bin_ = b_ih[2*DD + dp];
        const float bo   = b_out[0];

        bf16x8 wxr[4], wxz[4], wxn[4];
        #pragma unroll
        for (int kk = 0; kk < 4; ++kk) {
            wxr[kk] = W[((0  + pv)*4 + kk)*64 + lane];
            wxz[kk] = W[((8  + pv)*4 + kk)*64 + lane];
            wxn[kk] = W[((16 + pv)*4 + kk)*64 + lane];
        }

        const int pt  = tid & 511;
        const int gn  = pt >> 4;             // staging: seq 0..31
        const int gd8 = (pt & 15) * 8;       // staging: dim 0,8,..,120
        const float* xbase = x + ((size_t)(n0 + gn) * LL) * DD + gd8;

        // prologue: stage x_0 -> slot 0, x_1 -> slot 1
        pack8(*(const float4*)(xbase), *(const float4*)(xbase + 4),
              &xhx[gn * XP + gd8]);
        pack8(*(const float4*)(xbase + DD), *(const float4*)(xbase + DD + 4),
              &xhx[MS*XP + gn * XP + gd8]);

        __syncthreads();   // #1: staging done

        // prologue: gx[0] from x_0
        {
            const unsigned short* xr0 = &xhx[ln * XP];
            const unsigned short* xr1 = xr0 + 16*XP;
            f32x4 ar[2], az[2], an[2];
            #pragma unroll
            for (int tl = 0; tl < 2; ++tl) {
                ar[tl] = (f32x4){bir, bir, bir, bir};
                az[tl] = (f32x4){biz, biz, biz, biz};
                an[tl] = (f32x4){bin_, bin_, bin_, bin_};
            }
            #pragma unroll
            for (int kk = 0; kk < 4; ++kk) {
                bf16x8 a0 = *(const bf16x8*)(xr0 + kk*32 + q*8);
                bf16x8 a1 = *(const bf16x8*)(xr1 + kk*32 + q*8);
                ar[0] = MFMA(a0, wxr[kk], ar[0], 0,0,0);
                ar[1] = MFMA(a1, wxr[kk], ar[1], 0,0,0);
                az[0] = MFMA(a0, wxz[kk], az[0], 0,0,0);
                az[1] = MFMA(a1, wxz[kk], az[1], 0,0,0);
                an[0] = MFMA(a0, wxn[kk], an[0], 0,0,0);
                an[1] = MFMA(a1, wxn[kk], an[1], 0,0,0);
            }
            #pragma unroll
            for (int tl = 0; tl < 2; ++tl) {
                const int co = tl*16 + q*4;
                *(f32x4*)&gxs[(dp)*GP + co]        = ar[tl];
                *(f32x4*)&gxs[(DD + dp)*GP + co]   = az[tl];
                *(f32x4*)&gxs[(2*DD + dp)*GP + co] = an[tl];
            }
        }
        __syncthreads();   // #2: gx[0] ready

        for (int t = 0; t < LL; ++t) {
            // issue x_{t+2} loads early (latency hides under gx GEMM)
            float4 sa, sb;
            const int ts = t + 2;
            if (ts < LL) {
                sa = *(const float4*)(xbase + (size_t)ts * DD);
                sb = *(const float4*)(xbase + (size_t)ts * DD + 4);
            }
            // gx[t+1] from x_{t+1}
            if (t + 1 < LL) {
                const int sr = (t + 1) & 1;
                const unsigned short* xr0 = &xhx[sr*MS*XP + ln * XP];
                const unsigned short* xr1 = xr0 + 16*XP;
                f32x4 ar[2], az[2], an[2];
                #pragma unroll
                for (int tl = 0; tl < 2; ++tl) {
                    ar[tl] = (f32x4){bir, bir, bir, bir};
                    az[tl] = (f32x4){biz, biz, biz, biz};
                    an[tl] = (f32x4){bin_, bin_, bin_, bin_};
                }
                #pragma unroll
                for (int kk = 0; kk < 4; ++kk) {
                    bf16x8 a0 = *(const bf16x8*)(xr0 + kk*32 + q*8);
                    bf16x8 a1 = *(const bf16x8*)(xr1 + kk*32 + q*8);
                    ar[0] = MFMA(a0, wxr[kk], ar[0], 0,0,0);
                    ar[1] = MFMA(a1, wxr[kk], ar[1], 0,0,0);
                    az[0] = MFMA(a0, wxz[kk], az[0], 0,0,0);
                    az[1] = MFMA(a1, wxz[kk], az[1], 0,0,0);
                    an[0] = MFMA(a0, wxn[kk], an[0], 0,0,0);
                    an[1] = MFMA(a1, wxn[kk], an[1], 0,0,0);
                }
                float* gw = gxs + sr * GX_ELEMS;
                #pragma unroll
                for (int tl = 0; tl < 2; ++tl) {
                    const int co = tl*16 + q*4;
                    *(f32x4*)&gw[(dp)*GP + co]        = ar[tl];
                    *(f32x4*)&gw[(DD + dp)*GP + co]   = az[tl];
                    *(f32x4*)&gw[(2*DD + dp)*GP + co] = an[tl];
                }
            }
            // out[t-1] = h_{t-1} . w_out  (waves pv=0/1; tile = pv)
            if (pv < 2 && t >= 1) {
                f32x4 c4 = (f32x4){bo, bo, bo, bo};
                const unsigned short* hrw = &xhh[(t & 1)*MS*XP + (pv*16 + ln)*XP];
                #pragma unroll
                for (int kk = 0; kk < 4; ++kk) {
                    bf16x8 a = *(const bf16x8*)(hrw + kk*32 + q*8);
                    bf16x8 b = *(const bf16x8*)&wofl[(kk*64 + lane)*8];
                    c4 = MFMA(a, b, c4, 0,0,0);
                }
                if (ln == 0) {
                    #pragma unroll
                    for (int i = 0; i < 4; ++i)
                        outl[(pv*16 + q*4 + i)*OLP + (t - 1)] = c4[i];
                }
            }
            // late half of staging: pack + LDS write of x_{t+2}
            if (ts < LL)
                pack8(sa, sb, &xhx[(t & 1)*MS*XP + gn * XP + gd8]);

            __syncthreads();   // #3..#34
        }

        // final output column: out[31] = h_31 . w_out (h_31 in xhh slot 0)
        if (pv < 2) {
            f32x4 c4 = (f32x4){bo, bo, bo, bo};
            const unsigned short* hrw = &xhh[(pv*16 + ln)*XP];
            #pragma unroll
            for (int kk = 0; kk < 4; ++kk) {
                bf16x8 a = *(const bf16x8*)(hrw + kk*32 + q*8);
                bf16x8 b = *(const bf16x8*)&wofl[(kk*64 + lane)*8];
                c4 = MFMA(a, b, c4, 0,0,0);
            }
            if (ln == 0) {
                #pragma unroll
                for (int i = 0; i < 4; ++i)
                    outl[(pv*16 + q*4 + i)*OLP + (LL - 1)] = c4[i];
            }
        }
        __syncthreads();       // #35
    }
}

extern "C" void kernel_launch(void* const* d_in, const int* in_sizes, int n_in,
                              void* d_out, int out_size, void* d_ws, size_t ws_size,
                              hipStream_t stream) {
    const float* item  = (const float*)d_in[0];
    const float* user  = (const float*)d_in[1];
    const float* W_ih  = (const float*)d_in[2];
    const float* W_hh  = (const float*)d_in[3];
    const float* b_ih  = (const float*)d_in[4];
    const float* b_hh  = (const float*)d_in[5];
    const float* W_out = (const float*)d_in[6];
    const float* b_out = (const float*)d_in[7];
    float* out = (float*)d_out;

    unsigned short* Wfrag = (unsigned short*)d_ws;   // 192 frags * 512 = 98304 bf16

    static bool smem_cfg = false;
    if (!smem_cfg) {
        hipFuncSetAttribute((const void*)gru_mfma,
                            hipFuncAttributeMaxDynamicSharedMemorySize,
                            SMEM_TOTAL);
        smem_cfg = true;
    }

    prep_weights<<<384, 256, 0, stream>>>(W_ih, W_hh, Wfrag);
    gru_mfma<<<NSEQ / MS, NT, SMEM_TOTAL, stream>>>(item, user, Wfrag,
                                                    b_ih, b_hh, W_out, b_out, out);
}

// Round 2
// 219.567 us; speedup vs baseline: 1.0118x; 1.0118x over previous
//
#include <hip/hip_runtime.h>
#include <math.h>

#define DD   128      // hidden dim
#define LL   32       // sequence length
#define MS   32       // sequences per block
#define NT   1024     // 16 waves: 8 consumer + 8 producer
#define NSEQ 8192     // B*S
#define XP   136      // x/h LDS row pitch in ushorts (272 B, 16B-aligned)
#define OLP  36       // outl pitch in floats

// gx passes between producer/consumer as raw C-fragments:
//   [2 slots][48 tiles][64 lanes] x f32x4, tile = (g*8 + pv)*2 + st
// lane-linear 16B/lane -> every access is a contiguous 1KB wave access,
// bank-conflict-free by construction.
#define NFRAG      48
#define FRAGF      (NFRAG * 64 * 4)                   // floats per slot
#define SMEM_XH_X  (2 * FRAGF * 4)                    // 98304
#define SMEM_XH_H  (SMEM_XH_X + 2 * MS * XP * 2)      // +17408
#define SMEM_OUTL  (SMEM_XH_H + 2 * MS * XP * 2)      // +17408
#define SMEM_WOFL  (SMEM_OUTL + MS * OLP * 4)         // +4608
#define SMEM_TOTAL (SMEM_WOFL + 4 * 64 * 8 * 2)       // +4096 = 141824

typedef short bf16x8 __attribute__((ext_vector_type(8)));   // 8 bf16 = 4 VGPRs
typedef float f32x4  __attribute__((ext_vector_type(4)));

// Transposed orientation: A = weights (row = gate-dim), B = x/h (col = seq).
// A-frag and B-frag lane maps are identical, so the same Wfrag bytes and the
// same xh row-reads serve both; C now has col(lane&15)=seq, row(q*4+i)=dim.
#define MFMA __builtin_amdgcn_mfma_f32_16x16x32_bf16

__device__ __forceinline__ unsigned short f2bf(float f) {
    unsigned u = __float_as_uint(f);
    u += 0x7fffu + ((u >> 16) & 1u);          // round-to-nearest-even
    return (unsigned short)(u >> 16);
}

#if __has_builtin(__builtin_amdgcn_cvt_pk_bf16_f32)
typedef __bf16 bf16x2_t __attribute__((ext_vector_type(2)));
__device__ __forceinline__ unsigned pack2(float a, float b) {
    union { bf16x2_t v; unsigned u; } c;
    c.v = __builtin_amdgcn_cvt_pk_bf16_f32(a, b);
    return c.u;
}
#else
__device__ __forceinline__ unsigned pack2(float a, float b) {
    return (unsigned)f2bf(a) | ((unsigned)f2bf(b) << 16);
}
#endif

__device__ __forceinline__ void pack8(float4 a, float4 b, unsigned short* dst) {
    union { unsigned u[4]; bf16x8 v; } pk;
    pk.u[0] = pack2(a.x, a.y); pk.u[1] = pack2(a.z, a.w);
    pk.u[2] = pack2(b.x, b.y); pk.u[3] = pack2(b.z, b.w);
    *(bf16x8*)dst = pk.v;
}

__device__ __forceinline__ float fast_rcp(float x) {
    return __builtin_amdgcn_rcpf(x);   // v_rcp_f32, ~1 ulp — fine at bf16 output
}

// ---------------------------------------------------------------------------
// Prep: swizzle W_ih / W_hh into per-gate MFMA fragments, bf16.
// Frag index F = ((side*3 + g)*8 + sl)*4 + kk   (side 0=W_ih, 1=W_hh;
// g 0=r,1=z,2=n; sl = 16-dim slice 0..7; kk = K-subtile 0..3).
// Element j of lane (n=lane&15, q=lane>>4):
//   W_side[(g*128 + sl*16 + n) * 128 + (kk*32 + q*8 + j)]
// Used as the A-operand (row = gate-dim) in the transposed scheme.
// ---------------------------------------------------------------------------
__global__ void prep_weights(const float* __restrict__ Wih,
                             const float* __restrict__ Whh,
                             unsigned short* __restrict__ Wfrag) {
    int idx  = blockIdx.x * blockDim.x + threadIdx.x;   // 0 .. 98303
    int j    = idx & 7;
    int lane = (idx >> 3) & 63;
    int kk   = (idx >> 9) & 3;
    int sl   = (idx >> 11) & 7;
    int sg   = idx >> 14;            // 0..5 = side*3 + g
    int n = lane & 15, q = lane >> 4;
    int k  = kk * 32 + q * 8 + j;
    int g  = (sg >= 3) ? sg - 3 : sg;
    int gd = g * 128 + sl * 16 + n;
    const float* src = (sg >= 3) ? Whh : Wih;
    Wfrag[idx] = f2bf(src[gd * 128 + k]);
}

// ---------------------------------------------------------------------------
// Wave-specialized GRU, transposed MFMA orientation:
//   waves 0..7  (consumer): h-side GEMM + gate math + vectorized h-write.
//   waves 8..15 (producer): x staging, x-side GEMM 1 step ahead writing raw
//                           C-fragments to LDS, out-projection.
// Consumer reads the producer's fragments verbatim as accumulator init:
// zero layout conversion, zero bank conflicts on the gx path.
// ---------------------------------------------------------------------------
__global__ __launch_bounds__(NT, 4) void gru_mfma(
    const float* __restrict__ x,      // [8192][32][128]
    const float* __restrict__ h0,     // [8192][128]
    const unsigned short* __restrict__ Wfrag,
    const float* __restrict__ b_ih,   // [384]
    const float* __restrict__ b_hh,   // [384]
    const float* __restrict__ w_out,  // [128]
    const float* __restrict__ b_out,  // [1]
    float* __restrict__ out)          // [8192][32]
{
    extern __shared__ char smem[];
    float*          gxf  = (float*)(smem);                       // [2][48][64][4]
    unsigned short* xhx  = (unsigned short*)(smem + SMEM_XH_X);  // [2][MS][XP]
    unsigned short* xhh  = (unsigned short*)(smem + SMEM_XH_H);  // [2][MS][XP]
    float*          outl = (float*)(smem + SMEM_OUTL);           // [MS][OLP]
    unsigned short* wofl = (unsigned short*)(smem + SMEM_WOFL);  // [2048]

    const int tid  = threadIdx.x;
    const int n0   = blockIdx.x * MS;
    const int wv   = tid >> 6;       // 0..15
    const int lane = tid & 63;
    const int ln   = lane & 15;      // C col = seq within tile
    const int q    = lane >> 4;      // C rows q*4..q*4+3 = gate-dims
    const bf16x8* W = (const bf16x8*)Wfrag;

    if (wv < 8) {
        // ================= CONSUMER =================
        const int d4 = wv * 16 + q * 4;            // first of this lane's 4 dims
        const f32x4 bhn4 = *(const f32x4*)&b_hh[2*DD + d4];

        bf16x8 whr[4], whz[4], whn[4];             // A-operands (W_hh slices)
        #pragma unroll
        for (int kk = 0; kk < 4; ++kk) {
            whr[kk] = W[((24 + wv)*4 + kk)*64 + lane];
            whz[kk] = W[((32 + wv)*4 + kk)*64 + lane];
            whn[kk] = W[((40 + wv)*4 + kk)*64 + lane];
        }

        // stage W_out A-fragment (row 0 = w_out, rows 1..15 = 0)
        #pragma unroll
        for (int e = 0; e < 4; ++e) {
            int idx = tid * 4 + e;              // 0..2047
            int j   = idx & 7;
            int l2  = (idx >> 3) & 63;
            int kk  = idx >> 9;                 // 0..3
            int n2 = l2 & 15, q2 = l2 >> 4;
            wofl[idx] = (n2 == 0) ? f2bf(w_out[kk * 32 + q2 * 8 + j])
                                  : (unsigned short)0;
        }
        // stage h0 (bf16) into xhh slot 0
        {
            const int gn = tid >> 4, gd8 = (tid & 15) * 8;
            const float* hb = h0 + (size_t)(n0 + gn) * DD + gd8;
            pack8(*(const float4*)hb, *(const float4*)(hb + 4),
                  &xhh[gn * XP + gd8]);
        }
        // fp32 hidden state: lane=seq(ln), regs = dims d4..d4+3, per seq-tile st
        float4 hp0 = *(const float4*)&h0[(size_t)(n0 + ln) * DD + d4];
        float4 hp1 = *(const float4*)&h0[(size_t)(n0 + 16 + ln) * DD + d4];
        float hprev[8] = {hp0.x, hp0.y, hp0.z, hp0.w,
                          hp1.x, hp1.y, hp1.z, hp1.w};

        __syncthreads();   // #1: staging done
        __syncthreads();   // #2: gx[0] ready

        for (int t = 0; t < LL; ++t) {
            const int sl_ = t & 1;
            const float* gf = gxf + sl_ * FRAGF;
            f32x4 cr[2], cz[2], ch[2];
            #pragma unroll
            for (int st = 0; st < 2; ++st) {
                cr[st] = *(const f32x4*)&gf[(((0*8 + wv)*2 + st)*64 + lane)*4];
                cz[st] = *(const f32x4*)&gf[(((1*8 + wv)*2 + st)*64 + lane)*4];
                ch[st] = (f32x4){0.f, 0.f, 0.f, 0.f};
            }
            const unsigned short* hr0 = xhh + sl_*MS*XP + ln*XP;
            const unsigned short* hr1 = hr0 + 16*XP;
            __builtin_amdgcn_s_setprio(1);
            #pragma unroll
            for (int kk = 0; kk < 4; ++kk) {
                bf16x8 b0 = *(const bf16x8*)(hr0 + kk*32 + q*8);
                bf16x8 b1 = *(const bf16x8*)(hr1 + kk*32 + q*8);
                cr[0] = MFMA(whr[kk], b0, cr[0], 0,0,0);
                cr[1] = MFMA(whr[kk], b1, cr[1], 0,0,0);
                cz[0] = MFMA(whz[kk], b0, cz[0], 0,0,0);
                cz[1] = MFMA(whz[kk], b1, cz[1], 0,0,0);
                ch[0] = MFMA(whn[kk], b0, ch[0], 0,0,0);
                ch[1] = MFMA(whn[kk], b1, ch[1], 0,0,0);
            }
            __builtin_amdgcn_s_setprio(0);
            // n-gate x-side preacts read late (short live range)
            f32x4 gnx[2];
            #pragma unroll
            for (int st = 0; st < 2; ++st)
                gnx[st] = *(const f32x4*)&gf[(((2*8 + wv)*2 + st)*64 + lane)*4];

            unsigned short* hw = xhh + (sl_ ^ 1)*MS*XP;
            #pragma unroll
            for (int st = 0; st < 2; ++st) {
                float hh_[4];
                #pragma unroll
                for (int i = 0; i < 4; ++i) {
                    // r,z biases (b_ih + b_hh) baked into gx by the producer
                    const float rr = fast_rcp(1.f + __expf(-cr[st][i]));
                    const float zz = fast_rcp(1.f + __expf(-cz[st][i]));
                    const float aa = gnx[st][i] + rr * (ch[st][i] + bhn4[i]);
                    // tanh(aa) = 2/(1+exp(-2a)) - 1 : NaN-free
                    const float ee = __expf(-2.f * aa);
                    const float th = 2.f * fast_rcp(1.f + ee) - 1.f;
                    const float hh = th + zz * (hprev[st*4+i] - th);
                    hprev[st*4+i] = hh;
                    hh_[i] = hh;
                }
                union { unsigned u[2]; unsigned long long ull; } hv;
                hv.u[0] = pack2(hh_[0], hh_[1]);
                hv.u[1] = pack2(hh_[2], hh_[3]);
                *(unsigned long long*)&hw[(st*16 + ln)*XP + d4] = hv.ull;
            }
            __syncthreads();   // #3..#34
        }
        __syncthreads();       // #35: outl col 31 ready

        // coalesced flush: block's 32x32 outputs are contiguous in global
        if (tid < 256) {
            const int row = tid >> 3;
            const int t4  = (tid & 7) * 4;
            float4 v = *(const float4*)&outl[row * OLP + t4];
            *(float4*)(out + (size_t)(n0 + row) * LL + t4) = v;
        }
    } else {
        // ================= PRODUCER =================
        const int pv = wv - 8;
        const int d4 = pv * 16 + q * 4;
        // bake b_ih + b_hh into r,z; b_ih only into n (b_hh n-side is consumer's)
        f32x4 br4, bz4, bn4;
        {
            f32x4 a0 = *(const f32x4*)&b_ih[d4];
            f32x4 a1 = *(const f32x4*)&b_hh[d4];
            br4 = a0 + a1;
            a0 = *(const f32x4*)&b_ih[DD + d4];
            a1 = *(const f32x4*)&b_hh[DD + d4];
            bz4 = a0 + a1;
            bn4 = *(const f32x4*)&b_ih[2*DD + d4];
        }
        const float bo = b_out[0];

        bf16x8 wxr[4], wxz[4], wxn[4];             // A-operands (W_ih slices)
        #pragma unroll
        for (int kk = 0; kk < 4; ++kk) {
            wxr[kk] = W[((0  + pv)*4 + kk)*64 + lane];
            wxz[kk] = W[((8  + pv)*4 + kk)*64 + lane];
            wxn[kk] = W[((16 + pv)*4 + kk)*64 + lane];
        }

        const int pt  = tid & 511;
        const int gn  = pt >> 4;             // staging: seq 0..31
        const int gd8 = (pt & 15) * 8;       // staging: dim 0,8,..,120
        const float* xbase = x + ((size_t)(n0 + gn) * LL) * DD + gd8;

        // prologue: stage x_0 -> slot 0, x_1 -> slot 1
        pack8(*(const float4*)(xbase), *(const float4*)(xbase + 4),
              &xhx[gn * XP + gd8]);
        pack8(*(const float4*)(xbase + DD), *(const float4*)(xbase + DD + 4),
              &xhx[MS*XP + gn * XP + gd8]);

        __syncthreads();   // #1: staging done

#define GX_STEP(TT)                                                            \
        {                                                                      \
            const int sr = (TT) & 1;                                           \
            const unsigned short* xr0 = xhx + sr*MS*XP + ln*XP;                \
            const unsigned short* xr1 = xr0 + 16*XP;                           \
            f32x4 ar[2], az[2], an[2];                                         \
            ar[0] = br4; ar[1] = br4;                                          \
            az[0] = bz4; az[1] = bz4;                                          \
            an[0] = bn4; an[1] = bn4;                                          \
            _Pragma("unroll")                                                  \
            for (int kk = 0; kk < 4; ++kk) {                                   \
                bf16x8 b0 = *(const bf16x8*)(xr0 + kk*32 + q*8);               \
                bf16x8 b1 = *(const bf16x8*)(xr1 + kk*32 + q*8);               \
                ar[0] = MFMA(wxr[kk], b0, ar[0], 0,0,0);                       \
                ar[1] = MFMA(wxr[kk], b1, ar[1], 0,0,0);                       \
                az[0] = MFMA(wxz[kk], b0, az[0], 0,0,0);                       \
                az[1] = MFMA(wxz[kk], b1, az[1], 0,0,0);                       \
                an[0] = MFMA(wxn[kk], b0, an[0], 0,0,0);                       \
                an[1] = MFMA(wxn[kk], b1, an[1], 0,0,0);                       \
            }                                                                  \
            float* gw = gxf + sr * FRAGF;                                      \
            _Pragma("unroll")                                                  \
            for (int st = 0; st < 2; ++st) {                                   \
                *(f32x4*)&gw[(((0*8 + pv)*2 + st)*64 + lane)*4] = ar[st];      \
                *(f32x4*)&gw[(((1*8 + pv)*2 + st)*64 + lane)*4] = az[st];      \
                *(f32x4*)&gw[(((2*8 + pv)*2 + st)*64 + lane)*4] = an[st];      \
            }                                                                  \
        }

        // prologue: gx[0] from x_0
        GX_STEP(0)
        __syncthreads();   // #2: gx[0] ready

        for (int t = 0; t < LL; ++t) {
            // issue x_{t+2} loads early (latency hides under gx GEMM)
            float4 sa, sb;
            const int ts = t + 2;
            if (ts < LL) {
                sa = *(const float4*)(xbase + (size_t)ts * DD);
                sb = *(const float4*)(xbase + (size_t)ts * DD + 4);
            }
            // gx[t+1] from x_{t+1}
            if (t + 1 < LL) GX_STEP(t + 1)

            // out[t-1] = h_{t-1} . w_out  (waves pv=0/1; seq-tile = pv)
            if (pv < 2 && t >= 1) {
                f32x4 c4 = (f32x4){bo, bo, bo, bo};
                const unsigned short* hrw = xhh + (t & 1)*MS*XP + (pv*16 + ln)*XP;
                #pragma unroll
                for (int kk = 0; kk < 4; ++kk) {
                    bf16x8 a = *(const bf16x8*)&wofl[(kk*64 + lane)*8];
                    bf16x8 b = *(const bf16x8*)(hrw + kk*32 + q*8);
                    c4 = MFMA(a, b, c4, 0,0,0);
                }
                if (q == 0)                       // C row 0 lives in q=0, i=0
                    outl[(pv*16 + ln)*OLP + (t - 1)] = c4[0];
            }
            // late half of staging: pack + LDS write of x_{t+2}
            if (ts < LL)
                pack8(sa, sb, &xhx[(t & 1)*MS*XP + gn * XP + gd8]);

            __syncthreads();   // #3..#34
        }

        // final output column: out[31] = h_31 . w_out (h_31 in xhh slot 0)
        if (pv < 2) {
            f32x4 c4 = (f32x4){bo, bo, bo, bo};
            const unsigned short* hrw = xhh + (pv*16 + ln)*XP;
            #pragma unroll
            for (int kk = 0; kk < 4; ++kk) {
                bf16x8 a = *(const bf16x8*)&wofl[(kk*64 + lane)*8];
                bf16x8 b = *(const bf16x8*)(hrw + kk*32 + q*8);
                c4 = MFMA(a, b, c4, 0,0,0);
            }
            if (q == 0)
                outl[(pv*16 + ln)*OLP + (LL - 1)] = c4[0];
        }
        __syncthreads();       // #35
#undef GX_STEP
    }
}

extern "C" void kernel_launch(void* const* d_in, const int* in_sizes, int n_in,
                              void* d_out, int out_size, void* d_ws, size_t ws_size,
                              hipStream_t stream) {
    const float* item  = (const float*)d_in[0];
    const float* user  = (const float*)d_in[1];
    const float* W_ih  = (const float*)d_in[2];
    const float* W_hh  = (const float*)d_in[3];
    const float* b_ih  = (const float*)d_in[4];
    const float* b_hh  = (const float*)d_in[5];
    const float* W_out = (const float*)d_in[6];
    const float* b_out = (const float*)d_in[7];
    float* out = (float*)d_out;

    unsigned short* Wfrag = (unsigned short*)d_ws;   // 192 frags * 512 = 98304 bf16

    static bool smem_cfg = false;
    if (!smem_cfg) {
        hipFuncSetAttribute((const void*)gru_mfma,
                            hipFuncAttributeMaxDynamicSharedMemorySize,
                            SMEM_TOTAL);
        smem_cfg = true;
    }

    prep_weights<<<384, 256, 0, stream>>>(W_ih, W_hh, Wfrag);
    gru_mfma<<<NSEQ / MS, NT, SMEM_TOTAL, stream>>>(item, user, Wfrag,
                                                    b_ih, b_hh, W_out, b_out, out);
}